// Round 15
// baseline (327.557 us; speedup 1.0000x reference)
//
#include <hip/hip_runtime.h>
#include <math.h>

#define BB   4
#define TT   2048
#define DIMM 1024
#define NHH  16
#define HDD  64
#define MM   (BB * TT)  // 8192

typedef unsigned short u16;
typedef unsigned int   u32;
typedef short bf16x8 __attribute__((ext_vector_type(8)));  // 8 bf16 = 4 VGPRs
typedef float f32x4  __attribute__((ext_vector_type(4)));

__device__ __forceinline__ u16 f2bf(float f) {  // round-to-nearest-even
    u32 u = __float_as_uint(f);
    return (u16)((u + 0x7fffu + ((u >> 16) & 1u)) >> 16);
}

__device__ __forceinline__ f32x4 mfma16(bf16x8 a, bf16x8 b, f32x4 c) {
    return __builtin_amdgcn_mfma_f32_16x16x32_bf16(a, b, c, 0, 0, 0);
}

// raw HW exp2: v_exp_f32 computes D = 2^S0. Flush-to-zero for very negative
// args is fine for softmax; +inf propagates into the overflow fallback.
__device__ __forceinline__ float exp2_raw(float x) {
    float r;
    asm("v_exp_f32 %0, %1" : "=v"(r) : "v"(x));
    return r;
}

// swizzle for 128-byte-stride LDS rows (64 bf16/row, 8 slots of 16B)
__device__ __forceinline__ int swz8(int row, int slot) {
    return ((slot ^ (row & 7) ^ ((row >> 3) & 7)) & 7) * 8;
}
// swizzle for 64-byte-stride LDS rows (32 bf16/row, 4 slots of 16B)
__device__ __forceinline__ int swz4(int row, int slot) {
    return ((slot ^ (row & 3)) & 3) * 8;
}

// ---------------------------------------------------------------------------
// Fused preamble: z<4 -> W[k][n] fp32 -> Wt[n][k] bf16 (32x32 tile transpose);
// z==4 -> x fp32 -> bf16 straight convert (4 chunks per block).
// ---------------------------------------------------------------------------
__global__ void prep_w_x(const float* __restrict__ W0,
                         const float* __restrict__ W1,
                         const float* __restrict__ W2,
                         const float* __restrict__ W3,
                         u16* __restrict__ T0, u16* __restrict__ T1,
                         u16* __restrict__ T2, u16* __restrict__ T3,
                         const float* __restrict__ x, u16* __restrict__ xb) {
    __shared__ float tile[32][33];
    const int z   = blockIdx.z;
    const int tid = threadIdx.x;
    if (z == 4) {
        const int bid = blockIdx.y * 32 + blockIdx.x;
#pragma unroll
        for (int c = 0; c < 4; ++c) {
            int i = ((bid * 4 + c) * 256 + tid) * 8;
            float4 a = *(const float4*)(x + i);
            float4 b = *(const float4*)(x + i + 4);
            u32 w0 = f2bf(a.x) | ((u32)f2bf(a.y) << 16);
            u32 w1 = f2bf(a.z) | ((u32)f2bf(a.w) << 16);
            u32 w2 = f2bf(b.x) | ((u32)f2bf(b.y) << 16);
            u32 w3 = f2bf(b.z) | ((u32)f2bf(b.w) << 16);
            *(uint4*)(xb + i) = make_uint4(w0, w1, w2, w3);
        }
        return;
    }
    const float* W = (z == 0) ? W0 : (z == 1) ? W1 : (z == 2) ? W2 : W3;
    u16*        Wt = (z == 0) ? T0 : (z == 1) ? T1 : (z == 2) ? T2 : T3;
    const int c  = tid & 31;
    const int r8 = tid >> 5;   // 0..7
    const int kb = blockIdx.y * 32, nb = blockIdx.x * 32;
#pragma unroll
    for (int rr = 0; rr < 4; ++rr) {
        int r = r8 + rr * 8;
        tile[r][c] = W[(kb + r) * 1024 + nb + c];
    }
    __syncthreads();
#pragma unroll
    for (int rr = 0; rr < 4; ++rr) {
        int r = r8 + rr * 8;
        Wt[(nb + r) * 1024 + kb + c] = f2bf(tile[c][r]);
    }
}

// ---------------------------------------------------------------------------
// FUSED QKV GEMM: C[8192, 3072] = x @ [Wq|Wk|Wv] + bias, Bt = wcat[3072][1024].
// 128x128 tile, BK=32, 256 thr = 4 waves. Epilogue mode by n0>>10 (uniform):
//   mode 0: Q -> bf16 scatter [b,h,t,d], * qscale (0.125*log2e)
//   mode 1: K -> bf16 scatter [b,h,t,d]
//   mode 2: V -> bf16 transposed scatter [b,h,d,t], 8B packed stores
// ---------------------------------------------------------------------------
__global__ __launch_bounds__(256, 2) void gemm_qkv(
    const u16* __restrict__ A, const u16* __restrict__ Bt,
    const float* __restrict__ bq, const float* __restrict__ bk,
    const float* __restrict__ bv,
    u16* __restrict__ Qout, u16* __restrict__ Kout, u16* __restrict__ Vout,
    float qscale)
{
    __shared__ u16 As[128 * 32];
    __shared__ u16 Bs[128 * 32];

    const int tid  = threadIdx.x;
    const int m0   = blockIdx.x * 128;
    const int n0   = blockIdx.y * 128;
    const int wave = tid >> 6, lane = tid & 63;
    const int wr = wave >> 1, wc = wave & 1;
    const int l15 = lane & 15, l4 = lane >> 4;

    const int r0 = tid >> 2, ks = tid & 3;
    const int r1 = r0 + 64;
    const int w0 = r0 * 32 + swz4(r0, ks);
    const int w1 = r1 * 32 + swz4(r1, ks);

    f32x4 acc[4][4];
#pragma unroll
    for (int i = 0; i < 4; ++i)
#pragma unroll
        for (int j = 0; j < 4; ++j) acc[i][j] = (f32x4){0.f, 0.f, 0.f, 0.f};

    const u16* Ar0 = A  + (m0 + r0) * 1024 + ks * 8;
    const u16* Ar1 = A  + (m0 + r1) * 1024 + ks * 8;
    const u16* Br0 = Bt + (n0 + r0) * 1024 + ks * 8;
    const u16* Br1 = Bt + (n0 + r1) * 1024 + ks * 8;

    uint4 a0 = *(const uint4*)Ar0;
    uint4 a1 = *(const uint4*)Ar1;
    uint4 b0 = *(const uint4*)Br0;
    uint4 b1 = *(const uint4*)Br1;
    *(uint4*)&As[w0] = a0; *(uint4*)&As[w1] = a1;
    *(uint4*)&Bs[w0] = b0; *(uint4*)&Bs[w1] = b1;
    __syncthreads();

    for (int kt = 0; kt < 32; ++kt) {
        if (kt < 31) {
            const int ko = (kt + 1) * 32;
            a0 = *(const uint4*)(Ar0 + ko);
            a1 = *(const uint4*)(Ar1 + ko);
            b0 = *(const uint4*)(Br0 + ko);
            b1 = *(const uint4*)(Br1 + ko);
        }
        bf16x8 af[4], bf[4];
#pragma unroll
        for (int rt = 0; rt < 4; ++rt) {
            int row = wr * 64 + rt * 16 + l15;
            af[rt] = *(const bf16x8*)&As[row * 32 + swz4(row, l4)];
            int col = wc * 64 + rt * 16 + l15;
            bf[rt] = *(const bf16x8*)&Bs[col * 32 + swz4(col, l4)];
        }
#pragma unroll
        for (int rt = 0; rt < 4; ++rt)
#pragma unroll
            for (int ct = 0; ct < 4; ++ct)
                acc[rt][ct] = mfma16(af[rt], bf[ct], acc[rt][ct]);
        __syncthreads();
        if (kt < 31) {
            *(uint4*)&As[w0] = a0; *(uint4*)&As[w1] = a1;
            *(uint4*)&Bs[w0] = b0; *(uint4*)&Bs[w1] = b1;
            __syncthreads();
        }
    }

    // epilogue: mode is block-uniform (N-tile 128 divides 1024)
    const int mode = n0 >> 10;
    const float* bias = (mode == 0) ? bq : (mode == 1) ? bk : bv;
    const float osc = (mode == 0) ? qscale : 1.0f;
    u16* Sout = (mode == 0) ? Qout : Kout;

#pragma unroll
    for (int rt = 0; rt < 4; ++rt)
#pragma unroll
        for (int ct = 0; ct < 4; ++ct) {
            int n  = n0 + wc * 64 + ct * 16 + l15;
            int nn = n & 1023;
            float bn = bias[nn];
            int h = nn >> 6, d = nn & 63;
            if (mode == 2) {
                // V^T: pack 4 consecutive tokens into one 8B store
                int m00 = m0 + wr * 64 + rt * 16 + l4 * 4;
                int b = m00 >> 11, t0 = m00 & 2047;
                ushort4 pk;
                pk.x = f2bf(acc[rt][ct][0] + bn);
                pk.y = f2bf(acc[rt][ct][1] + bn);
                pk.z = f2bf(acc[rt][ct][2] + bn);
                pk.w = f2bf(acc[rt][ct][3] + bn);
                *(ushort4*)(&Vout[((((b << 4) + h) * 64 + d) << 11) + t0]) = pk;
            } else {
#pragma unroll
                for (int i = 0; i < 4; ++i) {
                    int m = m0 + wr * 64 + rt * 16 + l4 * 4 + i;
                    int b = m >> 11, t = m & 2047;
                    Sout[(((b << 4) + h) * 2048 + t) * 64 + d] =
                        f2bf((acc[rt][ct][i] + bn) * osc);
                }
            }
        }
}

// ---------------------------------------------------------------------------
// Out-projection GEMM: C[8192,1024] fp32 = obuf @ Wo^T + bo (row-major out).
// ---------------------------------------------------------------------------
__global__ __launch_bounds__(256, 2) void gemm_out(
    const u16* __restrict__ A, const u16* __restrict__ Bt,
    const float* __restrict__ bias, float* __restrict__ Cout)
{
    __shared__ u16 As[128 * 32];
    __shared__ u16 Bs[128 * 32];

    const int tid  = threadIdx.x;
    const int m0   = blockIdx.x * 128;
    const int n0   = blockIdx.y * 128;
    const int wave = tid >> 6, lane = tid & 63;
    const int wr = wave >> 1, wc = wave & 1;
    const int l15 = lane & 15, l4 = lane >> 4;

    const int r0 = tid >> 2, ks = tid & 3;
    const int r1 = r0 + 64;
    const int w0 = r0 * 32 + swz4(r0, ks);
    const int w1 = r1 * 32 + swz4(r1, ks);

    f32x4 acc[4][4];
#pragma unroll
    for (int i = 0; i < 4; ++i)
#pragma unroll
        for (int j = 0; j < 4; ++j) acc[i][j] = (f32x4){0.f, 0.f, 0.f, 0.f};

    const u16* Ar0 = A  + (m0 + r0) * 1024 + ks * 8;
    const u16* Ar1 = A  + (m0 + r1) * 1024 + ks * 8;
    const u16* Br0 = Bt + (n0 + r0) * 1024 + ks * 8;
    const u16* Br1 = Bt + (n0 + r1) * 1024 + ks * 8;

    uint4 a0 = *(const uint4*)Ar0;
    uint4 a1 = *(const uint4*)Ar1;
    uint4 b0 = *(const uint4*)Br0;
    uint4 b1 = *(const uint4*)Br1;
    *(uint4*)&As[w0] = a0; *(uint4*)&As[w1] = a1;
    *(uint4*)&Bs[w0] = b0; *(uint4*)&Bs[w1] = b1;
    __syncthreads();

    for (int kt = 0; kt < 32; ++kt) {
        if (kt < 31) {
            const int ko = (kt + 1) * 32;
            a0 = *(const uint4*)(Ar0 + ko);
            a1 = *(const uint4*)(Ar1 + ko);
            b0 = *(const uint4*)(Br0 + ko);
            b1 = *(const uint4*)(Br1 + ko);
        }
        bf16x8 af[4], bf[4];
#pragma unroll
        for (int rt = 0; rt < 4; ++rt) {
            int row = wr * 64 + rt * 16 + l15;
            af[rt] = *(const bf16x8*)&As[row * 32 + swz4(row, l4)];
            int col = wc * 64 + rt * 16 + l15;
            bf[rt] = *(const bf16x8*)&Bs[col * 32 + swz4(col, l4)];
        }
#pragma unroll
        for (int rt = 0; rt < 4; ++rt)
#pragma unroll
            for (int ct = 0; ct < 4; ++ct)
                acc[rt][ct] = mfma16(af[rt], bf[ct], acc[rt][ct]);
        __syncthreads();
        if (kt < 31) {
            *(uint4*)&As[w0] = a0; *(uint4*)&As[w1] = a1;
            *(uint4*)&Bs[w0] = b0; *(uint4*)&Bs[w1] = b1;
            __syncthreads();
        }
    }

#pragma unroll
    for (int rt = 0; rt < 4; ++rt)
#pragma unroll
        for (int ct = 0; ct < 4; ++ct) {
            int n = n0 + wc * 64 + ct * 16 + l15;
            float bn = bias[n];
#pragma unroll
            for (int i = 0; i < 4; ++i) {
                int m = m0 + wr * 64 + rt * 16 + l4 * 4 + i;
                Cout[m * 1024 + n] = acc[rt][ct][i] + bn;
            }
        }
}

// ---------------------------------------------------------------------------
// MFMA flash attention v8: round-14 structure + 2 Q-fragments per wave.
// Block = 128 q-rows of one (b,h); 256 thr = 4 waves; wave owns rows
// {wave*16..+16} and {64+wave*16..+16}. K-frags loaded once feed both
// S-MFMAs; softmax/PV per q-set sequential (Ps reused, wave-private).
// Staging/barriers per q-row halve. Grid 1024 = 4 blocks/CU exactly.
// ---------------------------------------------------------------------------
__global__ __launch_bounds__(256, 4) void attn_mfma(
    const u16* __restrict__ Qb, const u16* __restrict__ Kb,
    const u16* __restrict__ Vtg, u16* __restrict__ Ob)
{
    __shared__ u16 Ks[2][64 * 64];    // [buf][key][d], swizzled
    __shared__ u16 Vts[2][64 * 64];   // [buf][d][key], swizzled
    __shared__ u16 Ps[4][16 * 64];    // per-wave [q][key], swizzled (reused per q-set)

    const int tid   = threadIdx.x;
    // XCD-aware bijective swizzle for grid == 1024 (8 XCDs x 128 chunks).
    const int g     = blockIdx.x;
    const int chunk = (g & 7) * 128 + (g >> 3);
    const int bh    = chunk >> 4;          // 0..63 (16 q-tiles of 128 per bh)
    const int q0    = (chunk & 15) * 128;  // 0..1920
    const int b     = bh >> 4, h = bh & 15;
    const u16* Qp   = Qb + (bh * TT + q0) * HDD;
    const u16* Kp   = Kb + bh * TT * HDD;
    const u16* Vp   = Vtg + bh * TT * HDD;   // [d][t] per bh

    const int wave = tid >> 6, lane = tid & 63;
    const int l15 = lane & 15, l4 = lane >> 4;

    // Q B-frags, 2 q-sets: qf[qs][hf] = Q[q = qs*64 + wave*16 + l15][...]
    bf16x8 qf[2][2];
#pragma unroll
    for (int qs = 0; qs < 2; ++qs)
#pragma unroll
        for (int hf = 0; hf < 2; ++hf)
            qf[qs][hf] = *(const bf16x8*)(Qp + (qs * 64 + wave * 16 + l15) * HDD
                                          + hf * 32 + l4 * 8);

    f32x4 oacc[2][4];   // O[qs][q=l4*4+i][d=db*16+l15]
    float mr[2] = {-INFINITY, -INFINITY};
    float lr[2] = {0.f, 0.f};            // per-lane partials
#pragma unroll
    for (int qs = 0; qs < 2; ++qs)
#pragma unroll
        for (int db = 0; db < 4; ++db) oacc[qs][db] = (f32x4){0.f, 0.f, 0.f, 0.f};

    // P swizzle: slot' = slot ^ (l15&7) ^ ((l15>>3)<<2)
    const int pxor = (l15 & 7) ^ ((l15 >> 3) << 2);
    u32* const Pw = (u32*)&Ps[wave][0];
    int pidx[8];
#pragma unroll
    for (int nt = 0; nt < 4; ++nt)
#pragma unroll
        for (int pp = 0; pp < 2; ++pp) {
            int k2 = nt * 16 + l4 * 4 + 2 * pp;
            int slotW = ((k2 >> 3) ^ pxor) & 7;
            pidx[nt * 2 + pp] = (l15 * 64 + slotW * 8 + (k2 & 7)) >> 1;
        }
    int pread[2];
#pragma unroll
    for (int hf = 0; hf < 2; ++hf)
        pread[hf] = l15 * 64 + ((((hf << 2) + l4) ^ pxor) & 7) * 8;

    // staging: rows r0=tid>>3, r1=r0+32 (K: key-row; V^T: d-row), slot ds
    const int r0 = tid >> 3, ds = tid & 7;
    const int r1 = r0 + 32;
    const int wo0 = r0 * 64 + swz8(r0, ds);
    const int wo1 = r1 * 64 + swz8(r1, ds);

    uint4 kr0, kr1, vr0, vr1;
    kr0 = *(const uint4*)(Kp + r0 * 64 + ds * 8);
    kr1 = *(const uint4*)(Kp + r1 * 64 + ds * 8);
    vr0 = *(const uint4*)(Vp + r0 * 2048 + ds * 8);
    vr1 = *(const uint4*)(Vp + r1 * 2048 + ds * 8);
    *(uint4*)&Ks[0][wo0]  = kr0;
    *(uint4*)&Ks[0][wo1]  = kr1;
    *(uint4*)&Vts[0][wo0] = vr0;
    *(uint4*)&Vts[0][wo1] = vr1;
    __syncthreads();

    for (int kv = 0; kv < TT / 64; ++kv) {
        const int cur = kv & 1;

        // issue next tile's global loads; complete under compute (T14 split)
        if (kv < TT / 64 - 1) {
            const u16* Kt = Kp + (kv + 1) * 64 * HDD;
            const u16* Vt = Vp + (kv + 1) * 64;
            kr0 = *(const uint4*)(Kt + r0 * 64 + ds * 8);
            kr1 = *(const uint4*)(Kt + r1 * 64 + ds * 8);
            vr0 = *(const uint4*)(Vt + r0 * 2048 + ds * 8);
            vr1 = *(const uint4*)(Vt + r1 * 2048 + ds * 8);
        }

        // ---- S^T = K @ Q^T for BOTH q-sets; kf loaded once feeds both ----
        f32x4 sacc[2][4];
#pragma unroll
        for (int qs = 0; qs < 2; ++qs)
#pragma unroll
            for (int nt = 0; nt < 4; ++nt) sacc[qs][nt] = (f32x4){0.f, 0.f, 0.f, 0.f};
        __builtin_amdgcn_s_setprio(1);
#pragma unroll
        for (int nt = 0; nt < 4; ++nt) {
            int krow = nt * 16 + l15;
#pragma unroll
            for (int hf = 0; hf < 2; ++hf) {
                bf16x8 kf = *(const bf16x8*)&Ks[cur][krow * 64 + swz8(krow, hf * 4 + l4)];
                sacc[0][nt] = mfma16(kf, qf[0][hf], sacc[0][nt]);
                sacc[1][nt] = mfma16(kf, qf[1][hf], sacc[1][nt]);
            }
        }
        __builtin_amdgcn_s_setprio(0);

        // ---- per q-set: optimistic softmax + PV (Ps reused sequentially;
        // wave-private round-trip, no barrier between q-sets) ----
#pragma unroll
        for (int qs = 0; qs < 2; ++qs) {
            auto pack_pass = [&]() -> float {
                float ls0 = 0.f, ls1 = 0.f;
#pragma unroll
                for (int nt = 0; nt < 4; ++nt)
#pragma unroll
                    for (int pp = 0; pp < 2; ++pp) {
                        float pa = exp2_raw(sacc[qs][nt][2 * pp]     - mr[qs]);
                        float pb = exp2_raw(sacc[qs][nt][2 * pp + 1] - mr[qs]);
                        ls0 += pa; ls1 += pb;
                        u32 pk;
                        asm("v_cvt_pk_bf16_f32 %0, %1, %2" : "=v"(pk) : "v"(pa), "v"(pb));
                        Pw[pidx[nt * 2 + pp]] = pk;
                    }
                return ls0 + ls1;
            };
            float lsum = pack_pass();
            if (__builtin_expect(__any(!(lsum < 1e30f)), 0)) {
                float mx = sacc[qs][0][0];
#pragma unroll
                for (int nt = 0; nt < 4; ++nt)
#pragma unroll
                    for (int i = 0; i < 4; ++i) mx = fmaxf(mx, sacc[qs][nt][i]);
                mx = fmaxf(mx, __shfl_xor(mx, 16, 64));
                mx = fmaxf(mx, __shfl_xor(mx, 32, 64));
                float mnew = fmaxf(mr[qs], mx);
                float rsc  = (mr[qs] == -INFINITY) ? 0.f : exp2_raw(mr[qs] - mnew);
                mr[qs] = mnew;
                lr[qs] *= rsc;
                float rr[4];
#pragma unroll
                for (int i = 0; i < 4; ++i) rr[i] = __shfl(rsc, l4 * 4 + i, 16);
#pragma unroll
                for (int db = 0; db < 4; ++db)
#pragma unroll
                    for (int i = 0; i < 4; ++i) oacc[qs][db][i] *= rr[i];
                lsum = pack_pass();
            }
            lr[qs] += lsum;

            bf16x8 pf[2];
#pragma unroll
            for (int hf = 0; hf < 2; ++hf)
                pf[hf] = *(const bf16x8*)&Ps[wave][pread[hf]];
            __builtin_amdgcn_s_setprio(1);
#pragma unroll
            for (int db = 0; db < 4; ++db) {
                int d = db * 16 + l15;
#pragma unroll
                for (int hf = 0; hf < 2; ++hf) {
                    bf16x8 vf = *(const bf16x8*)&Vts[cur][d * 64 + swz8(d, hf * 4 + l4)];
                    oacc[qs][db] = mfma16(pf[hf], vf, oacc[qs][db]);
                }
            }
            __builtin_amdgcn_s_setprio(0);
        }

        // ---- stage next tile into the other buffer, single barrier ----
        if (kv < TT / 64 - 1) {
            const int nxt = cur ^ 1;
            *(uint4*)&Ks[nxt][wo0]  = kr0;
            *(uint4*)&Ks[nxt][wo1]  = kr1;
            *(uint4*)&Vts[nxt][wo0] = vr0;
            *(uint4*)&Vts[nxt][wo1] = vr1;
        }
        __syncthreads();
    }

    // epilogue: per q-set, reduce lr once, normalize, write
#pragma unroll
    for (int qs = 0; qs < 2; ++qs) {
        float lrq = lr[qs];
        lrq += __shfl_xor(lrq, 16, 64);
        lrq += __shfl_xor(lrq, 32, 64);
        float inv[4];
#pragma unroll
        for (int i = 0; i < 4; ++i) inv[i] = 1.f / __shfl(lrq, l4 * 4 + i, 16);
#pragma unroll
        for (int db = 0; db < 4; ++db)
#pragma unroll
            for (int i = 0; i < 4; ++i) {
                int t   = q0 + qs * 64 + wave * 16 + l4 * 4 + i;
                int col = h * 64 + db * 16 + l15;
                Ob[(b * TT + t) * DIMM + col] = f2bf(oacc[qs][db][i] * inv[i]);
            }
    }
}

extern "C" void kernel_launch(void* const* d_in, const int* in_sizes, int n_in,
                              void* d_out, int out_size, void* d_ws, size_t ws_size,
                              hipStream_t stream)
{
    const float* x  = (const float*)d_in[0];
    const float* Wq = (const float*)d_in[1];
    const float* bq = (const float*)d_in[2];
    const float* Wk = (const float*)d_in[3];
    const float* bk = (const float*)d_in[4];
    const float* Wv = (const float*)d_in[5];
    const float* bv = (const float*)d_in[6];
    const float* Wo = (const float*)d_in[7];
    const float* bo = (const float*)d_in[8];

    // ws layout (bf16): xb | wcat (Wq^T;Wk^T;Wv^T) | Wo^T | qbuf | obuf
    u16* xb   = (u16*)d_ws;              // 8192*1024
    u16* wcat = xb   + 8388608;          // 3072*1024
    u16* wot  = wcat + 3145728;          // 1024*1024
    u16* qbuf = wot  + 1048576;          // [bh][t][d], pre-scaled by 0.125*log2e
    u16* obuf = qbuf + 8388608;          // [8192][1024]
    // K ([bh][t][d]) and V^T ([bh][d][t]) live inside d_out (2 x 16.78 MB);
    // the final projection overwrites d_out only after attention consumed them.
    u16* kbuf = (u16*)d_out;
    u16* vbuf = kbuf + 8388608;

    prep_w_x<<<dim3(32, 32, 5), 256, 0, stream>>>(
        Wq, Wk, Wv, Wo, wcat, wcat + 1048576, wcat + 2097152, wot, x, xb);

    const float qscale = 0.125f * 1.44269504f;  // fold log2(e): softmax via exp2
    gemm_qkv<<<dim3(MM / 128, 3 * DIMM / 128), 256, 0, stream>>>(
        xb, wcat, bq, bk, bv, qbuf, kbuf, vbuf, qscale);

    attn_mfma<<<BB * NHH * (TT / 128), 256, 0, stream>>>(qbuf, kbuf, vbuf, obuf);

    gemm_out<<<dim3(MM / 128, DIMM / 128), 256, 0, stream>>>(obuf, wot, bo,
                                                             (float*)d_out);
}

// Round 16
// 221.048 us; speedup vs baseline: 1.4818x; 1.4818x over previous
//
#include <hip/hip_runtime.h>
#include <math.h>

#define BB   4
#define TT   2048
#define DIMM 1024
#define NHH  16
#define HDD  64
#define MM   (BB * TT)  // 8192

typedef unsigned short u16;
typedef unsigned int   u32;
typedef short bf16x8 __attribute__((ext_vector_type(8)));  // 8 bf16 = 4 VGPRs
typedef float f32x4  __attribute__((ext_vector_type(4)));

__device__ __forceinline__ u16 f2bf(float f) {  // round-to-nearest-even
    u32 u = __float_as_uint(f);
    return (u16)((u + 0x7fffu + ((u >> 16) & 1u)) >> 16);
}

__device__ __forceinline__ f32x4 mfma16(bf16x8 a, bf16x8 b, f32x4 c) {
    return __builtin_amdgcn_mfma_f32_16x16x32_bf16(a, b, c, 0, 0, 0);
}

// raw HW exp2: v_exp_f32 computes D = 2^S0 (cdna4_isa §3). Skips the OCML
// denormal-range guard sequence; flush-to-zero for very negative args is
// fine for softmax, +inf propagates (feeds the overflow fallback).
__device__ __forceinline__ float exp2_raw(float x) {
    float r;
    asm("v_exp_f32 %0, %1" : "=v"(r) : "v"(x));
    return r;
}

// swizzle for 128-byte-stride LDS rows (64 bf16/row, 8 slots of 16B)
__device__ __forceinline__ int swz8(int row, int slot) {
    return ((slot ^ (row & 7) ^ ((row >> 3) & 7)) & 7) * 8;
}
// swizzle for 64-byte-stride LDS rows (32 bf16/row, 4 slots of 16B)
__device__ __forceinline__ int swz4(int row, int slot) {
    return ((slot ^ (row & 3)) & 3) * 8;
}

// ---------------------------------------------------------------------------
// Fused preamble: z<4 -> W[k][n] fp32 -> Wt[n][k] bf16 (32x32 tile transpose);
// z==4 -> x fp32 -> bf16 straight convert (4 grid-strided chunks per block).
// ---------------------------------------------------------------------------
__global__ void prep_w_x(const float* __restrict__ W0,
                         const float* __restrict__ W1,
                         const float* __restrict__ W2,
                         const float* __restrict__ W3,
                         u16* __restrict__ T0, u16* __restrict__ T1,
                         u16* __restrict__ T2, u16* __restrict__ T3,
                         const float* __restrict__ x, u16* __restrict__ xb) {
    __shared__ float tile[32][33];
    const int z   = blockIdx.z;
    const int tid = threadIdx.x;
    if (z == 4) {
        // convert path: 1024 (x,y) blocks x 4 chunks x 256 thr x 8 elems = 8.4M
        const int bid = blockIdx.y * 32 + blockIdx.x;
#pragma unroll
        for (int c = 0; c < 4; ++c) {
            int i = ((bid * 4 + c) * 256 + tid) * 8;
            float4 a = *(const float4*)(x + i);
            float4 b = *(const float4*)(x + i + 4);
            u32 w0 = f2bf(a.x) | ((u32)f2bf(a.y) << 16);
            u32 w1 = f2bf(a.z) | ((u32)f2bf(a.w) << 16);
            u32 w2 = f2bf(b.x) | ((u32)f2bf(b.y) << 16);
            u32 w3 = f2bf(b.z) | ((u32)f2bf(b.w) << 16);
            *(uint4*)(xb + i) = make_uint4(w0, w1, w2, w3);
        }
        return;
    }
    const float* W = (z == 0) ? W0 : (z == 1) ? W1 : (z == 2) ? W2 : W3;
    u16*        Wt = (z == 0) ? T0 : (z == 1) ? T1 : (z == 2) ? T2 : T3;
    const int c  = tid & 31;
    const int r8 = tid >> 5;   // 0..7
    const int kb = blockIdx.y * 32, nb = blockIdx.x * 32;
#pragma unroll
    for (int rr = 0; rr < 4; ++rr) {
        int r = r8 + rr * 8;
        tile[r][c] = W[(kb + r) * 1024 + nb + c];
    }
    __syncthreads();
#pragma unroll
    for (int rr = 0; rr < 4; ++rr) {
        int r = r8 + rr * 8;
        Wt[(nb + r) * 1024 + kb + c] = f2bf(tile[c][r]);
    }
}

// ---------------------------------------------------------------------------
// FUSED QKV GEMM: C[8192, 3072] = x @ [Wq|Wk|Wv] + bias, Bt = wcat[3072][1024].
// 128x128 tile, BK=32, 256 thr = 4 waves. Epilogue mode by n0>>10 (uniform):
//   mode 0: Q -> bf16 scatter [b,h,t,d], * qscale (0.125*log2e)
//   mode 1: K -> bf16 scatter [b,h,t,d]
//   mode 2: V -> bf16 transposed scatter [b,h,d,t], 8B packed stores
// (round-11 reg-staged structure, verbatim — measured best)
// ---------------------------------------------------------------------------
__global__ __launch_bounds__(256, 2) void gemm_qkv(
    const u16* __restrict__ A, const u16* __restrict__ Bt,
    const float* __restrict__ bq, const float* __restrict__ bk,
    const float* __restrict__ bv,
    u16* __restrict__ Qout, u16* __restrict__ Kout, u16* __restrict__ Vout,
    float qscale)
{
    __shared__ u16 As[128 * 32];
    __shared__ u16 Bs[128 * 32];

    const int tid  = threadIdx.x;
    const int m0   = blockIdx.x * 128;
    const int n0   = blockIdx.y * 128;
    const int wave = tid >> 6, lane = tid & 63;
    const int wr = wave >> 1, wc = wave & 1;
    const int l15 = lane & 15, l4 = lane >> 4;

    const int r0 = tid >> 2, ks = tid & 3;
    const int r1 = r0 + 64;
    const int w0 = r0 * 32 + swz4(r0, ks);
    const int w1 = r1 * 32 + swz4(r1, ks);

    f32x4 acc[4][4];
#pragma unroll
    for (int i = 0; i < 4; ++i)
#pragma unroll
        for (int j = 0; j < 4; ++j) acc[i][j] = (f32x4){0.f, 0.f, 0.f, 0.f};

    const u16* Ar0 = A  + (m0 + r0) * 1024 + ks * 8;
    const u16* Ar1 = A  + (m0 + r1) * 1024 + ks * 8;
    const u16* Br0 = Bt + (n0 + r0) * 1024 + ks * 8;
    const u16* Br1 = Bt + (n0 + r1) * 1024 + ks * 8;

    uint4 a0 = *(const uint4*)Ar0;
    uint4 a1 = *(const uint4*)Ar1;
    uint4 b0 = *(const uint4*)Br0;
    uint4 b1 = *(const uint4*)Br1;
    *(uint4*)&As[w0] = a0; *(uint4*)&As[w1] = a1;
    *(uint4*)&Bs[w0] = b0; *(uint4*)&Bs[w1] = b1;
    __syncthreads();

    for (int kt = 0; kt < 32; ++kt) {
        if (kt < 31) {
            const int ko = (kt + 1) * 32;
            a0 = *(const uint4*)(Ar0 + ko);
            a1 = *(const uint4*)(Ar1 + ko);
            b0 = *(const uint4*)(Br0 + ko);
            b1 = *(const uint4*)(Br1 + ko);
        }
        bf16x8 af[4], bf[4];
#pragma unroll
        for (int rt = 0; rt < 4; ++rt) {
            int row = wr * 64 + rt * 16 + l15;
            af[rt] = *(const bf16x8*)&As[row * 32 + swz4(row, l4)];
            int col = wc * 64 + rt * 16 + l15;
            bf[rt] = *(const bf16x8*)&Bs[col * 32 + swz4(col, l4)];
        }
#pragma unroll
        for (int rt = 0; rt < 4; ++rt)
#pragma unroll
            for (int ct = 0; ct < 4; ++ct)
                acc[rt][ct] = mfma16(af[rt], bf[ct], acc[rt][ct]);
        __syncthreads();
        if (kt < 31) {
            *(uint4*)&As[w0] = a0; *(uint4*)&As[w1] = a1;
            *(uint4*)&Bs[w0] = b0; *(uint4*)&Bs[w1] = b1;
            __syncthreads();
        }
    }

    // epilogue: mode is block-uniform (N-tile 128 divides 1024)
    const int mode = n0 >> 10;
    const float* bias = (mode == 0) ? bq : (mode == 1) ? bk : bv;
    const float osc = (mode == 0) ? qscale : 1.0f;
    u16* Sout = (mode == 0) ? Qout : Kout;

#pragma unroll
    for (int rt = 0; rt < 4; ++rt)
#pragma unroll
        for (int ct = 0; ct < 4; ++ct) {
            int n  = n0 + wc * 64 + ct * 16 + l15;
            int nn = n & 1023;
            float bn = bias[nn];
            int h = nn >> 6, d = nn & 63;
            if (mode == 2) {
                // V^T: pack 4 consecutive tokens into one 8B store
                int m00 = m0 + wr * 64 + rt * 16 + l4 * 4;
                int b = m00 >> 11, t0 = m00 & 2047;
                ushort4 pk;
                pk.x = f2bf(acc[rt][ct][0] + bn);
                pk.y = f2bf(acc[rt][ct][1] + bn);
                pk.z = f2bf(acc[rt][ct][2] + bn);
                pk.w = f2bf(acc[rt][ct][3] + bn);
                *(ushort4*)(&Vout[((((b << 4) + h) * 64 + d) << 11) + t0]) = pk;
            } else {
#pragma unroll
                for (int i = 0; i < 4; ++i) {
                    int m = m0 + wr * 64 + rt * 16 + l4 * 4 + i;
                    int b = m >> 11, t = m & 2047;
                    Sout[(((b << 4) + h) * 2048 + t) * 64 + d] =
                        f2bf((acc[rt][ct][i] + bn) * osc);
                }
            }
        }
}

// ---------------------------------------------------------------------------
// Out-projection GEMM: C[8192,1024] fp32 = obuf @ Wo^T + bo (row-major out).
// (round-11 reg-staged structure, verbatim)
// ---------------------------------------------------------------------------
__global__ __launch_bounds__(256, 2) void gemm_out(
    const u16* __restrict__ A, const u16* __restrict__ Bt,
    const float* __restrict__ bias, float* __restrict__ Cout)
{
    __shared__ u16 As[128 * 32];
    __shared__ u16 Bs[128 * 32];

    const int tid  = threadIdx.x;
    const int m0   = blockIdx.x * 128;
    const int n0   = blockIdx.y * 128;
    const int wave = tid >> 6, lane = tid & 63;
    const int wr = wave >> 1, wc = wave & 1;
    const int l15 = lane & 15, l4 = lane >> 4;

    const int r0 = tid >> 2, ks = tid & 3;
    const int r1 = r0 + 64;
    const int w0 = r0 * 32 + swz4(r0, ks);
    const int w1 = r1 * 32 + swz4(r1, ks);

    f32x4 acc[4][4];
#pragma unroll
    for (int i = 0; i < 4; ++i)
#pragma unroll
        for (int j = 0; j < 4; ++j) acc[i][j] = (f32x4){0.f, 0.f, 0.f, 0.f};

    const u16* Ar0 = A  + (m0 + r0) * 1024 + ks * 8;
    const u16* Ar1 = A  + (m0 + r1) * 1024 + ks * 8;
    const u16* Br0 = Bt + (n0 + r0) * 1024 + ks * 8;
    const u16* Br1 = Bt + (n0 + r1) * 1024 + ks * 8;

    uint4 a0 = *(const uint4*)Ar0;
    uint4 a1 = *(const uint4*)Ar1;
    uint4 b0 = *(const uint4*)Br0;
    uint4 b1 = *(const uint4*)Br1;
    *(uint4*)&As[w0] = a0; *(uint4*)&As[w1] = a1;
    *(uint4*)&Bs[w0] = b0; *(uint4*)&Bs[w1] = b1;
    __syncthreads();

    for (int kt = 0; kt < 32; ++kt) {
        if (kt < 31) {
            const int ko = (kt + 1) * 32;
            a0 = *(const uint4*)(Ar0 + ko);
            a1 = *(const uint4*)(Ar1 + ko);
            b0 = *(const uint4*)(Br0 + ko);
            b1 = *(const uint4*)(Br1 + ko);
        }
        bf16x8 af[4], bf[4];
#pragma unroll
        for (int rt = 0; rt < 4; ++rt) {
            int row = wr * 64 + rt * 16 + l15;
            af[rt] = *(const bf16x8*)&As[row * 32 + swz4(row, l4)];
            int col = wc * 64 + rt * 16 + l15;
            bf[rt] = *(const bf16x8*)&Bs[col * 32 + swz4(col, l4)];
        }
#pragma unroll
        for (int rt = 0; rt < 4; ++rt)
#pragma unroll
            for (int ct = 0; ct < 4; ++ct)
                acc[rt][ct] = mfma16(af[rt], bf[ct], acc[rt][ct]);
        __syncthreads();
        if (kt < 31) {
            *(uint4*)&As[w0] = a0; *(uint4*)&As[w1] = a1;
            *(uint4*)&Bs[w0] = b0; *(uint4*)&Bs[w1] = b1;
            __syncthreads();
        }
    }

#pragma unroll
    for (int rt = 0; rt < 4; ++rt)
#pragma unroll
        for (int ct = 0; ct < 4; ++ct) {
            int n = n0 + wc * 64 + ct * 16 + l15;
            float bn = bias[n];
#pragma unroll
            for (int i = 0; i < 4; ++i) {
                int m = m0 + wr * 64 + rt * 16 + l4 * 4 + i;
                Cout[m * 1024 + n] = acc[rt][ct][i] + bn;
            }
        }
}

// ---------------------------------------------------------------------------
// MFMA flash attention (round-14 version, verbatim — best measured 131 us):
// swapped QK^T, optimistic softmax (per-lane overflow check; lr per-lane
// partial, reduced once in epilogue), raw v_exp_f32, cvt_pk P-packing,
// per-wave LDS P round-trip, V^T global layout, reg-prefetch double-buffered
// K/V LDS, 1 barrier/tile. Block = 64 q-rows; 256 thr = 4 waves.
// Q pre-scaled by 0.125*log2(e) -> softmax in exp2 domain.
// NOTE (r15 post-mortem): widening to 2 q-sets/wave spills (WRITE_SIZE 555MB)
// — the 4-wave barrier-synced structure is at its plateau; do not widen.
// ---------------------------------------------------------------------------
__global__ __launch_bounds__(256, 4) void attn_mfma(
    const u16* __restrict__ Qb, const u16* __restrict__ Kb,
    const u16* __restrict__ Vtg, u16* __restrict__ Ob)
{
    __shared__ u16 Ks[2][64 * 64];    // [buf][key][d], swizzled
    __shared__ u16 Vts[2][64 * 64];   // [buf][d][key], swizzled
    __shared__ u16 Ps[4][16 * 64];    // per-wave [q][key], swizzled

    const int tid   = threadIdx.x;
    // XCD-aware bijective swizzle for grid == 2048 (8 XCDs x 256 chunks).
    const int g     = blockIdx.x;
    const int chunk = (g & 7) * 256 + (g >> 3);
    const int bh    = chunk >> 5;          // 0..63
    const int q0    = (chunk & 31) * 64;   // 0..1984
    const int b     = bh >> 4, h = bh & 15;
    const u16* Qp   = Qb + (bh * TT + q0) * HDD;
    const u16* Kp   = Kb + bh * TT * HDD;
    const u16* Vp   = Vtg + bh * TT * HDD;   // [d][t] per bh

    const int wave = tid >> 6, lane = tid & 63;
    const int l15 = lane & 15, l4 = lane >> 4;

    // Q B-frags: lane holds Q[q=wave*16+l15][d=hf*32+l4*8+j]
    bf16x8 qf[2];
#pragma unroll
    for (int hf = 0; hf < 2; ++hf)
        qf[hf] = *(const bf16x8*)(Qp + (wave * 16 + l15) * HDD + hf * 32 + l4 * 8);

    f32x4 oacc[4];   // O[q=l4*4+i][d=db*16+l15]
    float mr = -INFINITY, lr = 0.f;   // mr: running max (q=l15); lr: PER-LANE partial
#pragma unroll
    for (int db = 0; db < 4; ++db) oacc[db] = (f32x4){0.f, 0.f, 0.f, 0.f};

    // P swizzle: slot' = slot ^ (l15&7) ^ ((l15>>3)<<2)
    const int pxor = (l15 & 7) ^ ((l15 >> 3) << 2);
    u32* const Pw = (u32*)&Ps[wave][0];
    int pidx[8];   // dword indices for the 8 packed P stores (kv-invariant)
#pragma unroll
    for (int nt = 0; nt < 4; ++nt)
#pragma unroll
        for (int pp = 0; pp < 2; ++pp) {
            int k2 = nt * 16 + l4 * 4 + 2 * pp;
            int slotW = ((k2 >> 3) ^ pxor) & 7;
            pidx[nt * 2 + pp] = (l15 * 64 + slotW * 8 + (k2 & 7)) >> 1;
        }
    int pread[2];  // u16 offsets for the 2 b128 P-frag reads
#pragma unroll
    for (int hf = 0; hf < 2; ++hf)
        pread[hf] = l15 * 64 + ((((hf << 2) + l4) ^ pxor) & 7) * 8;

    // staging: rows r0=tid>>3, r1=r0+32 (K: key-row; V^T: d-row), slot ds
    const int r0 = tid >> 3, ds = tid & 7;
    const int r1 = r0 + 32;
    const int wo0 = r0 * 64 + swz8(r0, ds);
    const int wo1 = r1 * 64 + swz8(r1, ds);

    uint4 kr0, kr1, vr0, vr1;
    // prologue: tile 0
    kr0 = *(const uint4*)(Kp + r0 * 64 + ds * 8);
    kr1 = *(const uint4*)(Kp + r1 * 64 + ds * 8);
    vr0 = *(const uint4*)(Vp + r0 * 2048 + ds * 8);
    vr1 = *(const uint4*)(Vp + r1 * 2048 + ds * 8);
    *(uint4*)&Ks[0][wo0]  = kr0;
    *(uint4*)&Ks[0][wo1]  = kr1;
    *(uint4*)&Vts[0][wo0] = vr0;
    *(uint4*)&Vts[0][wo1] = vr1;
    __syncthreads();

    for (int kv = 0; kv < TT / 64; ++kv) {
        const int cur = kv & 1;

        // issue next tile's global loads; complete under compute (T14 split)
        if (kv < TT / 64 - 1) {
            const u16* Kt = Kp + (kv + 1) * 64 * HDD;
            const u16* Vt = Vp + (kv + 1) * 64;
            kr0 = *(const uint4*)(Kt + r0 * 64 + ds * 8);
            kr1 = *(const uint4*)(Kt + r1 * 64 + ds * 8);
            vr0 = *(const uint4*)(Vt + r0 * 2048 + ds * 8);
            vr1 = *(const uint4*)(Vt + r1 * 2048 + ds * 8);
        }

        // ---- S^T = K @ Q^T : lane holds S[key=nt*16+l4*4+i][q=l15] ----
        f32x4 sacc[4];
#pragma unroll
        for (int nt = 0; nt < 4; ++nt) sacc[nt] = (f32x4){0.f, 0.f, 0.f, 0.f};
        __builtin_amdgcn_s_setprio(1);
#pragma unroll
        for (int nt = 0; nt < 4; ++nt) {
            int krow = nt * 16 + l15;
#pragma unroll
            for (int hf = 0; hf < 2; ++hf) {
                bf16x8 kf = *(const bf16x8*)&Ks[cur][krow * 64 + swz8(krow, hf * 4 + l4)];
                sacc[nt] = mfma16(kf, qf[hf], sacc[nt]);
            }
        }
        __builtin_amdgcn_s_setprio(0);

        // ---- optimistic softmax: raw v_exp_f32 with (possibly stale) mr,
        // cvt_pk pack, store. Per-lane overflow check (inf/NaN via !(x<1e30));
        // lr stays a per-lane partial — cross-lane reduced once in epilogue.
        auto pack_pass = [&]() -> float {
            float ls0 = 0.f, ls1 = 0.f;
#pragma unroll
            for (int nt = 0; nt < 4; ++nt)
#pragma unroll
                for (int pp = 0; pp < 2; ++pp) {
                    float pa = exp2_raw(sacc[nt][2 * pp]     - mr);
                    float pb = exp2_raw(sacc[nt][2 * pp + 1] - mr);
                    ls0 += pa; ls1 += pb;
                    u32 pk;
                    asm("v_cvt_pk_bf16_f32 %0, %1, %2" : "=v"(pk) : "v"(pa), "v"(pb));
                    Pw[pidx[nt * 2 + pp]] = pk;
                }
            return ls0 + ls1;
        };
        float lsum = pack_pass();
        if (__builtin_expect(__any(!(lsum < 1e30f)), 0)) {
            // fallback: true max, rescale state, recompute P
            float mx = sacc[0][0];
#pragma unroll
            for (int nt = 0; nt < 4; ++nt)
#pragma unroll
                for (int i = 0; i < 4; ++i) mx = fmaxf(mx, sacc[nt][i]);
            mx = fmaxf(mx, __shfl_xor(mx, 16, 64));
            mx = fmaxf(mx, __shfl_xor(mx, 32, 64));
            float mnew = fmaxf(mr, mx);
            float rsc  = (mr == -INFINITY) ? 0.f : exp2_raw(mr - mnew);
            mr = mnew;
            lr *= rsc;                       // per-lane partial scales uniformly
            float rr[4];
#pragma unroll
            for (int i = 0; i < 4; ++i) rr[i] = __shfl(rsc, l4 * 4 + i, 16);
#pragma unroll
            for (int db = 0; db < 4; ++db)
#pragma unroll
                for (int i = 0; i < 4; ++i) oacc[db][i] *= rr[i];
            lsum = pack_pass();
        }
        lr += lsum;

        // ---- O += P @ V (P round-trip is wave-private: no barrier needed) ----
        bf16x8 pf[2];
#pragma unroll
        for (int hf = 0; hf < 2; ++hf)
            pf[hf] = *(const bf16x8*)&Ps[wave][pread[hf]];
        __builtin_amdgcn_s_setprio(1);
#pragma unroll
        for (int db = 0; db < 4; ++db) {
            int d = db * 16 + l15;
#pragma unroll
            for (int hf = 0; hf < 2; ++hf) {
                bf16x8 vf = *(const bf16x8*)&Vts[cur][d * 64 + swz8(d, hf * 4 + l4)];
                oacc[db] = mfma16(pf[hf], vf, oacc[db]);
            }
        }
        __builtin_amdgcn_s_setprio(0);

        // ---- stage next tile into the other buffer, single barrier ----
        if (kv < TT / 64 - 1) {
            const int nxt = cur ^ 1;
            *(uint4*)&Ks[nxt][wo0]  = kr0;
            *(uint4*)&Ks[nxt][wo1]  = kr1;
            *(uint4*)&Vts[nxt][wo0] = vr0;
            *(uint4*)&Vts[nxt][wo1] = vr1;
        }
        __syncthreads();
    }

    // epilogue: reduce lr across the 4 lane-groups ONCE, then per-row shuffle
    lr += __shfl_xor(lr, 16, 64);
    lr += __shfl_xor(lr, 32, 64);
    float inv[4];
#pragma unroll
    for (int i = 0; i < 4; ++i) inv[i] = 1.f / __shfl(lr, l4 * 4 + i, 16);
#pragma unroll
    for (int db = 0; db < 4; ++db)
#pragma unroll
        for (int i = 0; i < 4; ++i) {
            int t   = q0 + wave * 16 + l4 * 4 + i;
            int col = h * 64 + db * 16 + l15;
            Ob[(b * TT + t) * DIMM + col] = f2bf(oacc[db][i] * inv[i]);
        }
}

extern "C" void kernel_launch(void* const* d_in, const int* in_sizes, int n_in,
                              void* d_out, int out_size, void* d_ws, size_t ws_size,
                              hipStream_t stream)
{
    const float* x  = (const float*)d_in[0];
    const float* Wq = (const float*)d_in[1];
    const float* bq = (const float*)d_in[2];
    const float* Wk = (const float*)d_in[3];
    const float* bk = (const float*)d_in[4];
    const float* Wv = (const float*)d_in[5];
    const float* bv = (const float*)d_in[6];
    const float* Wo = (const float*)d_in[7];
    const float* bo = (const float*)d_in[8];

    // ws layout (bf16): xb | wcat (Wq^T;Wk^T;Wv^T) | Wo^T | qbuf | obuf
    u16* xb   = (u16*)d_ws;              // 8192*1024
    u16* wcat = xb   + 8388608;          // 3072*1024
    u16* wot  = wcat + 3145728;          // 1024*1024
    u16* qbuf = wot  + 1048576;          // [bh][t][d], pre-scaled by 0.125*log2e
    u16* obuf = qbuf + 8388608;          // [8192][1024]
    // K ([bh][t][d]) and V^T ([bh][d][t]) live inside d_out (2 x 16.78 MB);
    // the final projection overwrites d_out only after attention consumed them.
    u16* kbuf = (u16*)d_out;
    u16* vbuf = kbuf + 8388608;

    prep_w_x<<<dim3(32, 32, 5), 256, 0, stream>>>(
        Wq, Wk, Wv, Wo, wcat, wcat + 1048576, wcat + 2097152, wot, x, xb);

    const float qscale = 0.125f * 1.44269504f;  // fold log2(e): softmax via exp2
    gemm_qkv<<<dim3(MM / 128, 3 * DIMM / 128), 256, 0, stream>>>(
        xb, wcat, bq, bk, bv, qbuf, kbuf, vbuf, qscale);

    attn_mfma<<<BB * NHH * (TT / 64), 256, 0, stream>>>(qbuf, kbuf, vbuf, obuf);

    gemm_out<<<dim3(MM / 128, DIMM / 128), 256, 0, stream>>>(obuf, wot, bo,
                                                             (float*)d_out);
}